// Round 4
// baseline (772.149 us; speedup 1.0000x reference)
//
#include <hip/hip_runtime.h>
#include <hip/hip_fp16.h>

#define NFEAT 128

typedef _Float16 v8hf __attribute__((ext_vector_type(8)));
typedef float v4f __attribute__((ext_vector_type(4)));

// ---------------- degree histogram + per-edge rank ----------------
__global__ void k_deg_rank(const int* __restrict__ dst, int* __restrict__ deg,
                           int* __restrict__ rank, int E) {
  int e = blockIdx.x * blockDim.x + threadIdx.x;
  if (e < E) rank[e] = atomicAdd(&deg[dst[e]], 1);
}

// ---------------- W transpose + fp16 cast: Wt[n][k] = half(W[k][n]) ----------
__global__ void k_prep_w(const float* __restrict__ W1, const float* __restrict__ W2,
                         _Float16* __restrict__ Wt1, _Float16* __restrict__ Wt2) {
  int idx = blockIdx.x * 256 + threadIdx.x;     // 0..32767
  const float* W = (idx < 16384) ? W1 : W2;
  _Float16* Wt = (idx < 16384) ? Wt1 : Wt2;
  int i = idx & 16383;
  int k = i >> 7, n = i & 127;
  Wt[n * 128 + k] = (_Float16)W[k * 128 + n];
}

// ---------------- 2-level exclusive scan ----------------
__global__ __launch_bounds__(1024) void k_scan_blocks(const int* __restrict__ deg,
    int* __restrict__ base, int* __restrict__ partials, int n) {
  __shared__ int buf[1024];
  int tid = threadIdx.x;
  int i = blockIdx.x * 1024 + tid;
  int v = (i < n) ? deg[i] : 0;
  buf[tid] = v;
  __syncthreads();
  #pragma unroll
  for (int off = 1; off < 1024; off <<= 1) {
    int t = (tid >= off) ? buf[tid - off] : 0;
    __syncthreads();
    buf[tid] += t;
    __syncthreads();
  }
  if (i < n) base[i] = buf[tid] - v;
  if (tid == 1023) partials[blockIdx.x] = buf[tid];
}

__global__ void k_scan_partials(int* __restrict__ partials, int nb) {
  __shared__ int buf[128];
  int tid = threadIdx.x;
  int v = (tid < nb) ? partials[tid] : 0;
  buf[tid] = v;
  __syncthreads();
  #pragma unroll
  for (int off = 1; off < 128; off <<= 1) {
    int t = (tid >= off) ? buf[tid - off] : 0;
    __syncthreads();
    buf[tid] += t;
    __syncthreads();
  }
  if (tid < nb) partials[tid] = buf[tid] - v;
}

__global__ void k_finalize_base(int* __restrict__ base, const int* __restrict__ partials,
    const int* __restrict__ deg, float* __restrict__ dinv, int n, int E) {
  int i = blockIdx.x * blockDim.x + threadIdx.x;
  if (i < n) {
    base[i] += partials[i >> 10];
    dinv[i] = rsqrtf((float)(deg[i] + 1));
  } else if (i == n) {
    base[n] = E;
  }
}

__global__ void k_scatter(const int* __restrict__ src, const int* __restrict__ dst,
    const int* __restrict__ rank, const int* __restrict__ base,
    int* __restrict__ ssrc, int E) {
  int e = blockIdx.x * blockDim.x + threadIdx.x;
  if (e < E) ssrc[base[dst[e]] + rank[e]] = src[e];
}

// ---------------- MFMA fp16 GEMM: g16 = sliced( (A @ W) * dinv[row] ) ---------
// Block: 64 rows x 128 cols, 256 threads (4 waves, 16 rows each). Whole K=128
// staged in LDS (A cast to fp16, Wt pre-transposed n-major fp16). 8 column
// tiles x 4 k-steps of mfma_f32_16x16x32_f16 per wave.
// Output layout: slice s = col/16 : g16[(s*N + row)*16 + col%16]  (fp16).
template <typename AT>
__global__ __launch_bounds__(256) void k_gemm_mfma(
    const AT* __restrict__ A, const _Float16* __restrict__ Wt,
    const float* __restrict__ dinv, _Float16* __restrict__ g16, int N) {
  __shared__ _Float16 As[64][136];   // pad 8 halves: row stride 272 B
  __shared__ _Float16 Ws[128][136];  // Ws[n][k]
  const int tid = threadIdx.x;
  const int row0 = blockIdx.x * 64;

  if constexpr (sizeof(AT) == 4) {   // fp32 input: load + cast
    #pragma unroll
    for (int i = 0; i < 8; i++) {
      int idx = tid + i * 256;       // 0..2047
      int row = idx >> 5;            // 0..63
      int c4 = idx & 31;             // float4 col
      int gr = row0 + row; gr = (gr < N) ? gr : (N - 1);
      float4 v = *(const float4*)((const float*)A + (size_t)gr * NFEAT + c4 * 4);
      _Float16* p = &As[row][c4 * 4];
      p[0] = (_Float16)v.x; p[1] = (_Float16)v.y;
      p[2] = (_Float16)v.z; p[3] = (_Float16)v.w;
    }
  } else {                           // fp16 input: straight copy
    #pragma unroll
    for (int i = 0; i < 4; i++) {
      int idx = tid + i * 256;       // 0..1023
      int row = idx >> 4;            // 0..63
      int c8 = idx & 15;             // 8-half chunk
      int gr = row0 + row; gr = (gr < N) ? gr : (N - 1);
      *(uint4*)&As[row][c8 * 8] =
          *(const uint4*)((const _Float16*)A + (size_t)gr * NFEAT + c8 * 8);
    }
  }
  #pragma unroll
  for (int i = 0; i < 8; i++) {
    int idx = tid + i * 256;         // 0..2047
    int row = idx >> 4;              // 0..127
    int c8 = idx & 15;
    *(uint4*)&Ws[row][c8 * 8] = *(const uint4*)(Wt + (size_t)row * 128 + c8 * 8);
  }
  __syncthreads();

  const int wv = tid >> 6;
  const int lane = tid & 63;
  const int m = lane & 15;           // A row within 16 / B col within 16
  const int q = lane >> 4;           // quad: k-group, D row-group

  v4f acc[8] = {};
  const _Float16* arow = &As[wv * 16 + m][0];
  #pragma unroll
  for (int kt = 0; kt < 4; kt++) {
    v8hf af = *(const v8hf*)(arow + kt * 32 + q * 8);
    #pragma unroll
    for (int ct = 0; ct < 8; ct++) {
      v8hf bf = *(const v8hf*)(&Ws[ct * 16 + m][kt * 32 + q * 8]);
      acc[ct] = __builtin_amdgcn_mfma_f32_16x16x32_f16(af, bf, acc[ct], 0, 0, 0);
    }
  }

  int nd[4]; float dv[4];
  #pragma unroll
  for (int r = 0; r < 4; r++) {
    nd[r] = row0 + wv * 16 + q * 4 + r;
    int c = (nd[r] < N) ? nd[r] : (N - 1);
    dv[r] = dinv[c];
  }
  #pragma unroll
  for (int ct = 0; ct < 8; ct++)
    #pragma unroll
    for (int r = 0; r < 4; r++)
      if (nd[r] < N)
        g16[((size_t)ct * N + nd[r]) * 16 + m] = (_Float16)(acc[ct][r] * dv[r]);
}

// ---------------- XCD-sliced agg: slice s pinned via blockIdx%8 --------------
// Wave per node; 64 lanes = 8 edge-groups x 8 half2 features of one 16-feat
// slice. Butterfly (xor 8/16/32) sums groups. Layer-1: writes fp16 hB row.
__global__ __launch_bounds__(256) void k_agg_slice(
    const __half2* __restrict__ g16, const float* __restrict__ dinv,
    const int* __restrict__ base, const int* __restrict__ ssrc,
    const float* __restrict__ bias, __half2* __restrict__ hB, int N) {
  int lane = threadIdx.x & 63;
  int wv = threadIdx.x >> 6;
  int s = blockIdx.x & 7;
  int n = (blockIdx.x >> 3) * 4 + wv;
  if (n >= N) return;
  int g = lane >> 3, d = lane & 7;
  const __half2* table = g16 + (size_t)s * N * 8;
  int b0 = base[n], b1 = base[n + 1];
  float2 acc = make_float2(0.f, 0.f);
  if (g == 0) acc = __half22float2(table[(size_t)n * 8 + d]);   // self term
  for (int e = b0; e < b1; e += 16) {
    int e0 = e + g, e1 = e + 8 + g;
    if (e0 < b1) {
      float2 f = __half22float2(table[(size_t)ssrc[e0] * 8 + d]);
      acc.x += f.x; acc.y += f.y;
    }
    if (e1 < b1) {
      float2 f = __half22float2(table[(size_t)ssrc[e1] * 8 + d]);
      acc.x += f.x; acc.y += f.y;
    }
  }
  #pragma unroll
  for (int mask = 8; mask <= 32; mask <<= 1) {
    acc.x += __shfl_xor(acc.x, mask, 64);
    acc.y += __shfl_xor(acc.y, mask, 64);
  }
  float dvn = dinv[n];
  float2 bb = *(const float2*)(bias + s * 16 + d * 2);
  float rx = fmaxf(acc.x * dvn + bb.x, 0.f);
  float ry = fmaxf(acc.y * dvn + bb.y, 0.f);
  if (g == 0) hB[(size_t)n * 64 + s * 8 + d] = __floats2half2_rn(rx, ry);
}

// ---------------- layer-2 sliced agg fused with final linear -----------------
__global__ __launch_bounds__(256) void k_agg_final_slice(
    const __half2* __restrict__ g16, const float* __restrict__ dinv,
    const int* __restrict__ base, const int* __restrict__ ssrc,
    const float* __restrict__ bias, const float* __restrict__ wlin,
    const float* __restrict__ blin, float* __restrict__ out, int N) {
  int lane = threadIdx.x & 63;
  int wv = threadIdx.x >> 6;
  int s = blockIdx.x & 7;
  int n = (blockIdx.x >> 3) * 4 + wv;
  if (n >= N) return;
  int g = lane >> 3, d = lane & 7;
  const __half2* table = g16 + (size_t)s * N * 8;
  int b0 = base[n], b1 = base[n + 1];
  float2 acc = make_float2(0.f, 0.f);
  if (g == 0) acc = __half22float2(table[(size_t)n * 8 + d]);
  for (int e = b0; e < b1; e += 16) {
    int e0 = e + g, e1 = e + 8 + g;
    if (e0 < b1) {
      float2 f = __half22float2(table[(size_t)ssrc[e0] * 8 + d]);
      acc.x += f.x; acc.y += f.y;
    }
    if (e1 < b1) {
      float2 f = __half22float2(table[(size_t)ssrc[e1] * 8 + d]);
      acc.x += f.x; acc.y += f.y;
    }
  }
  #pragma unroll
  for (int mask = 8; mask <= 32; mask <<= 1) {
    acc.x += __shfl_xor(acc.x, mask, 64);
    acc.y += __shfl_xor(acc.y, mask, 64);
  }
  float dvn = dinv[n];
  float2 bb = *(const float2*)(bias + s * 16 + d * 2);
  float2 wl = *(const float2*)(wlin + s * 16 + d * 2);
  float p = fmaxf(acc.x * dvn + bb.x, 0.f) * wl.x +
            fmaxf(acc.y * dvn + bb.y, 0.f) * wl.y;
  #pragma unroll
  for (int mask = 1; mask <= 4; mask <<= 1) p += __shfl_xor(p, mask, 64);
  if (lane == 0) atomicAdd(out + n, p + (s == 0 ? blin[0] : 0.f));
}

extern "C" void kernel_launch(void* const* d_in, const int* in_sizes, int n_in,
                              void* d_out, int out_size, void* d_ws, size_t ws_size,
                              hipStream_t stream) {
  const float* x    = (const float*)d_in[0];
  const int*   ei   = (const int*)d_in[1];
  const float* W1   = (const float*)d_in[2];
  const float* b1   = (const float*)d_in[3];
  const float* W2   = (const float*)d_in[4];
  const float* b2   = (const float*)d_in[5];
  const float* Wlin = (const float*)d_in[6];
  const float* blin = (const float*)d_in[7];
  const int N = in_sizes[0] / NFEAT;
  const int E = in_sizes[1] / 2;
  const int* src = ei;
  const int* dst = ei + E;

  // workspace layout (4B units, 16B-aligned chunks)
  int* ws_i = (int*)d_ws;
  size_t off = 0;
  int* deg      = ws_i + off; off += N;
  int* base     = ws_i + off; off += (size_t)N + 1;
  off = (off + 3) & ~(size_t)3;
  int* partials = ws_i + off; off += 128;
  int* ssrc     = ws_i + off; off += E;
  float* dinv   = (float*)(ws_i + off); off += N;
  off = (off + 3) & ~(size_t)3;
  _Float16* Wt1 = (_Float16*)(ws_i + off); off += 8192;   // 128x128 fp16
  _Float16* Wt2 = (_Float16*)(ws_i + off); off += 8192;
  _Float16* g16 = (_Float16*)(ws_i + off); off += (size_t)N * 64;  // sliced table
  _Float16* hB  = (_Float16*)(ws_i + off); off += (size_t)N * 64;  // fp16 activations
  int* rank     = (int*)g16;   // E ints, consumed by k_scatter before GEMM1 writes g16

  hipMemsetAsync(deg, 0, (size_t)N * sizeof(int), stream);
  hipMemsetAsync(d_out, 0, (size_t)N * sizeof(float), stream);  // atomic target

  const int tpbE = 256;
  const int gE = (E + tpbE - 1) / tpbE;
  k_deg_rank<<<gE, tpbE, 0, stream>>>(dst, deg, rank, E);
  k_prep_w<<<128, 256, 0, stream>>>(W1, W2, Wt1, Wt2);

  const int nb = (N + 1023) / 1024;
  k_scan_blocks<<<nb, 1024, 0, stream>>>(deg, base, partials, N);
  k_scan_partials<<<1, 128, 0, stream>>>(partials, nb);
  k_finalize_base<<<((N + 1) + 255) / 256, 256, 0, stream>>>(base, partials, deg, dinv, N, E);
  k_scatter<<<gE, tpbE, 0, stream>>>(src, dst, rank, base, ssrc, E);

  const int gg = (N + 63) / 64;
  const int ga = 8 * ((N + 3) / 4);
  // layer 1
  k_gemm_mfma<float><<<gg, 256, 0, stream>>>(x, Wt1, dinv, g16, N);
  k_agg_slice<<<ga, 256, 0, stream>>>((const __half2*)g16, dinv, base, ssrc, b1,
                                      (__half2*)hB, N);
  // layer 2 + fused final linear
  k_gemm_mfma<_Float16><<<gg, 256, 0, stream>>>(hB, Wt2, dinv, g16, N);
  k_agg_final_slice<<<ga, 256, 0, stream>>>((const __half2*)g16, dinv, base, ssrc, b2,
                                            Wlin, blin, (float*)d_out, N);
}

// Round 5
// 628.378 us; speedup vs baseline: 1.2288x; 1.2288x over previous
//
#include <hip/hip_runtime.h>
#include <hip/hip_fp16.h>

#define NFEAT 128

typedef _Float16 v8hf __attribute__((ext_vector_type(8)));
typedef float v4f __attribute__((ext_vector_type(4)));

// ---------------- degree histogram + per-edge rank ----------------
__global__ void k_deg_rank(const int* __restrict__ dst, int* __restrict__ deg,
                           int* __restrict__ rank, int E) {
  int e = blockIdx.x * blockDim.x + threadIdx.x;
  if (e < E) rank[e] = atomicAdd(&deg[dst[e]], 1);
}

// ---------------- W transpose + fp16 cast: Wt[n][k] = half(W[k][n]) ----------
__global__ void k_prep_w(const float* __restrict__ W1, const float* __restrict__ W2,
                         _Float16* __restrict__ Wt1, _Float16* __restrict__ Wt2) {
  int idx = blockIdx.x * 256 + threadIdx.x;     // 0..32767
  const float* W = (idx < 16384) ? W1 : W2;
  _Float16* Wt = (idx < 16384) ? Wt1 : Wt2;
  int i = idx & 16383;
  int k = i >> 7, n = i & 127;
  Wt[n * 128 + k] = (_Float16)W[k * 128 + n];
}

// ---------------- 2-level exclusive scan ----------------
__global__ __launch_bounds__(1024) void k_scan_blocks(const int* __restrict__ deg,
    int* __restrict__ base, int* __restrict__ partials, int n) {
  __shared__ int buf[1024];
  int tid = threadIdx.x;
  int i = blockIdx.x * 1024 + tid;
  int v = (i < n) ? deg[i] : 0;
  buf[tid] = v;
  __syncthreads();
  #pragma unroll
  for (int off = 1; off < 1024; off <<= 1) {
    int t = (tid >= off) ? buf[tid - off] : 0;
    __syncthreads();
    buf[tid] += t;
    __syncthreads();
  }
  if (i < n) base[i] = buf[tid] - v;
  if (tid == 1023) partials[blockIdx.x] = buf[tid];
}

__global__ void k_scan_partials(int* __restrict__ partials, int nb) {
  __shared__ int buf[128];
  int tid = threadIdx.x;
  int v = (tid < nb) ? partials[tid] : 0;
  buf[tid] = v;
  __syncthreads();
  #pragma unroll
  for (int off = 1; off < 128; off <<= 1) {
    int t = (tid >= off) ? buf[tid - off] : 0;
    __syncthreads();
    buf[tid] += t;
    __syncthreads();
  }
  if (tid < nb) partials[tid] = buf[tid] - v;
}

__global__ void k_finalize_base(int* __restrict__ base, const int* __restrict__ partials,
    const int* __restrict__ deg, float* __restrict__ dinv, int n, int E) {
  int i = blockIdx.x * blockDim.x + threadIdx.x;
  if (i < n) {
    base[i] += partials[i >> 10];
    dinv[i] = rsqrtf((float)(deg[i] + 1));
  } else if (i == n) {
    base[n] = E;
  }
}

__global__ void k_scatter(const int* __restrict__ src, const int* __restrict__ dst,
    const int* __restrict__ rank, const int* __restrict__ base,
    int* __restrict__ ssrc, int E) {
  int e = blockIdx.x * blockDim.x + threadIdx.x;
  if (e < E) ssrc[base[dst[e]] + rank[e]] = src[e];
}

// ---------------- MFMA fp16 GEMM: g16 = sliced( (A @ W) * dinv[row] ) ---------
// Block: 64 rows x 128 cols, 256 threads (4 waves, 16 rows each). Whole K=128
// staged in LDS. Output layout: slice s = col/16 : g16[(s*N + row)*16 + col%16].
template <typename AT>
__global__ __launch_bounds__(256) void k_gemm_mfma(
    const AT* __restrict__ A, const _Float16* __restrict__ Wt,
    const float* __restrict__ dinv, _Float16* __restrict__ g16, int N) {
  __shared__ _Float16 As[64][136];
  __shared__ _Float16 Ws[128][136];
  const int tid = threadIdx.x;
  const int row0 = blockIdx.x * 64;

  if constexpr (sizeof(AT) == 4) {   // fp32 input: load + cast
    #pragma unroll
    for (int i = 0; i < 8; i++) {
      int idx = tid + i * 256;       // 0..2047
      int row = idx >> 5;
      int c4 = idx & 31;
      int gr = row0 + row; gr = (gr < N) ? gr : (N - 1);
      float4 v = *(const float4*)((const float*)A + (size_t)gr * NFEAT + c4 * 4);
      _Float16* p = &As[row][c4 * 4];
      p[0] = (_Float16)v.x; p[1] = (_Float16)v.y;
      p[2] = (_Float16)v.z; p[3] = (_Float16)v.w;
    }
  } else {                           // fp16 input: straight copy
    #pragma unroll
    for (int i = 0; i < 4; i++) {
      int idx = tid + i * 256;
      int row = idx >> 4;
      int c8 = idx & 15;
      int gr = row0 + row; gr = (gr < N) ? gr : (N - 1);
      *(uint4*)&As[row][c8 * 8] =
          *(const uint4*)((const _Float16*)A + (size_t)gr * NFEAT + c8 * 8);
    }
  }
  #pragma unroll
  for (int i = 0; i < 8; i++) {
    int idx = tid + i * 256;
    int row = idx >> 4;
    int c8 = idx & 15;
    *(uint4*)&Ws[row][c8 * 8] = *(const uint4*)(Wt + (size_t)row * 128 + c8 * 8);
  }
  __syncthreads();

  const int wv = tid >> 6;
  const int lane = tid & 63;
  const int m = lane & 15;
  const int q = lane >> 4;

  v4f acc[8] = {};
  const _Float16* arow = &As[wv * 16 + m][0];
  #pragma unroll
  for (int kt = 0; kt < 4; kt++) {
    v8hf af = *(const v8hf*)(arow + kt * 32 + q * 8);
    #pragma unroll
    for (int ct = 0; ct < 8; ct++) {
      v8hf bf = *(const v8hf*)(&Ws[ct * 16 + m][kt * 32 + q * 8]);
      acc[ct] = __builtin_amdgcn_mfma_f32_16x16x32_f16(af, bf, acc[ct], 0, 0, 0);
    }
  }

  int nd[4]; float dv[4];
  #pragma unroll
  for (int r = 0; r < 4; r++) {
    nd[r] = row0 + wv * 16 + q * 4 + r;
    int c = (nd[r] < N) ? nd[r] : (N - 1);
    dv[r] = dinv[c];
  }
  #pragma unroll
  for (int ct = 0; ct < 8; ct++)
    #pragma unroll
    for (int r = 0; r < 4; r++)
      if (nd[r] < N)
        g16[((size_t)ct * N + nd[r]) * 16 + m] = (_Float16)(acc[ct][r] * dv[r]);
}

// ---------------- XCD-sliced agg, 8 nodes per wave ---------------------------
// Block = 4 waves, pinned to slice s = blockIdx%8; wave handles 8 consecutive
// nodes. Lanes: g = lane>>3 (edge group), d = lane&7 (half2 feature within the
// 16-feature slice). One gather instr = 8 edges x 32 B = 256 B payload.
__global__ __launch_bounds__(256) void k_agg_slice(
    const __half2* __restrict__ g16, const float* __restrict__ dinv,
    const int* __restrict__ base, const int* __restrict__ ssrc,
    const float* __restrict__ bias, __half2* __restrict__ hB, int N) {
  int lane = threadIdx.x & 63;
  int wv = threadIdx.x >> 6;
  int s = blockIdx.x & 7;
  int n0 = (blockIdx.x >> 3) * 32 + wv * 8;
  if (n0 >= N) return;
  int g = lane >> 3, d = lane & 7;
  const __half2* table = g16 + (size_t)s * N * 8;
  float2 bb = *(const float2*)(bias + s * 16 + d * 2);   // hoisted per wave
  int nEnd = (n0 + 8 < N) ? (n0 + 8) : N;
  for (int n = n0; n < nEnd; n++) {
    int b0 = base[n], b1 = base[n + 1];
    float2 acc = make_float2(0.f, 0.f);
    if (g == 0) acc = __half22float2(table[(size_t)n * 8 + d]);  // self term
    int e = b0 + g;
    for (; e + 8 < b1; e += 16) {
      __half2 va = table[(size_t)ssrc[e] * 8 + d];
      __half2 vb = table[(size_t)ssrc[e + 8] * 8 + d];
      float2 fa = __half22float2(va), fb = __half22float2(vb);
      acc.x += fa.x + fb.x; acc.y += fa.y + fb.y;
    }
    if (e < b1) {
      float2 f = __half22float2(table[(size_t)ssrc[e] * 8 + d]);
      acc.x += f.x; acc.y += f.y;
    }
    #pragma unroll
    for (int mask = 8; mask <= 32; mask <<= 1) {
      acc.x += __shfl_xor(acc.x, mask, 64);
      acc.y += __shfl_xor(acc.y, mask, 64);
    }
    float dvn = dinv[n];
    float rx = fmaxf(acc.x * dvn + bb.x, 0.f);
    float ry = fmaxf(acc.y * dvn + bb.y, 0.f);
    if (g == 0) hB[(size_t)n * 64 + s * 8 + d] = __floats2half2_rn(rx, ry);
  }
}

// ---------------- layer-2 sliced agg fused with final linear -----------------
__global__ __launch_bounds__(256) void k_agg_final_slice(
    const __half2* __restrict__ g16, const float* __restrict__ dinv,
    const int* __restrict__ base, const int* __restrict__ ssrc,
    const float* __restrict__ bias, const float* __restrict__ wlin,
    const float* __restrict__ blin, float* __restrict__ out, int N) {
  int lane = threadIdx.x & 63;
  int wv = threadIdx.x >> 6;
  int s = blockIdx.x & 7;
  int n0 = (blockIdx.x >> 3) * 32 + wv * 8;
  if (n0 >= N) return;
  int g = lane >> 3, d = lane & 7;
  const __half2* table = g16 + (size_t)s * N * 8;
  float2 bb = *(const float2*)(bias + s * 16 + d * 2);
  float2 wl = *(const float2*)(wlin + s * 16 + d * 2);
  float bl0 = (s == 0) ? blin[0] : 0.f;
  int nEnd = (n0 + 8 < N) ? (n0 + 8) : N;
  for (int n = n0; n < nEnd; n++) {
    int b0 = base[n], b1 = base[n + 1];
    float2 acc = make_float2(0.f, 0.f);
    if (g == 0) acc = __half22float2(table[(size_t)n * 8 + d]);
    int e = b0 + g;
    for (; e + 8 < b1; e += 16) {
      __half2 va = table[(size_t)ssrc[e] * 8 + d];
      __half2 vb = table[(size_t)ssrc[e + 8] * 8 + d];
      float2 fa = __half22float2(va), fb = __half22float2(vb);
      acc.x += fa.x + fb.x; acc.y += fa.y + fb.y;
    }
    if (e < b1) {
      float2 f = __half22float2(table[(size_t)ssrc[e] * 8 + d]);
      acc.x += f.x; acc.y += f.y;
    }
    #pragma unroll
    for (int mask = 8; mask <= 32; mask <<= 1) {
      acc.x += __shfl_xor(acc.x, mask, 64);
      acc.y += __shfl_xor(acc.y, mask, 64);
    }
    float dvn = dinv[n];
    float p = fmaxf(acc.x * dvn + bb.x, 0.f) * wl.x +
              fmaxf(acc.y * dvn + bb.y, 0.f) * wl.y;
    #pragma unroll
    for (int mask = 1; mask <= 4; mask <<= 1) p += __shfl_xor(p, mask, 64);
    if (lane == 0) atomicAdd(out + n, p + bl0);
  }
}

extern "C" void kernel_launch(void* const* d_in, const int* in_sizes, int n_in,
                              void* d_out, int out_size, void* d_ws, size_t ws_size,
                              hipStream_t stream) {
  const float* x    = (const float*)d_in[0];
  const int*   ei   = (const int*)d_in[1];
  const float* W1   = (const float*)d_in[2];
  const float* b1   = (const float*)d_in[3];
  const float* W2   = (const float*)d_in[4];
  const float* b2   = (const float*)d_in[5];
  const float* Wlin = (const float*)d_in[6];
  const float* blin = (const float*)d_in[7];
  const int N = in_sizes[0] / NFEAT;
  const int E = in_sizes[1] / 2;
  const int* src = ei;
  const int* dst = ei + E;

  // workspace layout (4B units)
  int* ws_i = (int*)d_ws;
  size_t off = 0;
  int* deg      = ws_i + off; off += N;
  int* base     = ws_i + off; off += (size_t)N + 1;
  off = (off + 3) & ~(size_t)3;
  int* partials = ws_i + off; off += 128;
  int* ssrc     = ws_i + off; off += E;
  float* dinv   = (float*)(ws_i + off); off += N;
  off = (off + 3) & ~(size_t)3;
  _Float16* Wt1 = (_Float16*)(ws_i + off); off += 8192;
  _Float16* Wt2 = (_Float16*)(ws_i + off); off += 8192;
  _Float16* g16 = (_Float16*)(ws_i + off); off += (size_t)N * 64;
  _Float16* hB  = (_Float16*)(ws_i + off); off += (size_t)N * 64;
  int* rank     = (int*)g16;   // E ints, consumed before GEMM1 writes g16

  hipMemsetAsync(deg, 0, (size_t)N * sizeof(int), stream);
  hipMemsetAsync(d_out, 0, (size_t)N * sizeof(float), stream);

  const int tpbE = 256;
  const int gE = (E + tpbE - 1) / tpbE;
  k_deg_rank<<<gE, tpbE, 0, stream>>>(dst, deg, rank, E);
  k_prep_w<<<128, 256, 0, stream>>>(W1, W2, Wt1, Wt2);

  const int nb = (N + 1023) / 1024;
  k_scan_blocks<<<nb, 1024, 0, stream>>>(deg, base, partials, N);
  k_scan_partials<<<1, 128, 0, stream>>>(partials, nb);
  k_finalize_base<<<((N + 1) + 255) / 256, 256, 0, stream>>>(base, partials, deg, dinv, N, E);
  k_scatter<<<gE, tpbE, 0, stream>>>(src, dst, rank, base, ssrc, E);

  const int gg = (N + 63) / 64;
  const int ga = 8 * ((N + 31) / 32);
  // layer 1
  k_gemm_mfma<float><<<gg, 256, 0, stream>>>(x, Wt1, dinv, g16, N);
  k_agg_slice<<<ga, 256, 0, stream>>>((const __half2*)g16, dinv, base, ssrc, b1,
                                      (__half2*)hB, N);
  // layer 2 + fused final linear
  k_gemm_mfma<_Float16><<<gg, 256, 0, stream>>>(hB, Wt2, dinv, g16, N);
  k_agg_final_slice<<<ga, 256, 0, stream>>>((const __half2*)g16, dinv, base, ssrc, b2,
                                            Wlin, blin, (float*)d_out, N);
}

// Round 6
// 431.645 us; speedup vs baseline: 1.7888x; 1.4558x over previous
//
#include <hip/hip_runtime.h>
#include <hip/hip_fp16.h>

#define NFEAT 128

typedef _Float16 v8hf __attribute__((ext_vector_type(8)));
typedef float v4f __attribute__((ext_vector_type(4)));

// ---------------- degree histogram + per-edge rank ----------------
__global__ void k_deg_rank(const int* __restrict__ dst, int* __restrict__ deg,
                           int* __restrict__ rank, int E) {
  int e = blockIdx.x * blockDim.x + threadIdx.x;
  if (e < E) rank[e] = atomicAdd(&deg[dst[e]], 1);
}

// ---------------- W transpose + fp16 cast: Wt[n][k] = half(W[k][n]) ----------
__global__ void k_prep_w(const float* __restrict__ W1, const float* __restrict__ W2,
                         _Float16* __restrict__ Wt1, _Float16* __restrict__ Wt2) {
  int idx = blockIdx.x * 256 + threadIdx.x;     // 0..32767
  const float* W = (idx < 16384) ? W1 : W2;
  _Float16* Wt = (idx < 16384) ? Wt1 : Wt2;
  int i = idx & 16383;
  int k = i >> 7, n = i & 127;
  Wt[n * 128 + k] = (_Float16)W[k * 128 + n];
}

// ---------------- 2-level exclusive scan ----------------
__global__ __launch_bounds__(1024) void k_scan_blocks(const int* __restrict__ deg,
    int* __restrict__ base, int* __restrict__ partials, int n) {
  __shared__ int buf[1024];
  int tid = threadIdx.x;
  int i = blockIdx.x * 1024 + tid;
  int v = (i < n) ? deg[i] : 0;
  buf[tid] = v;
  __syncthreads();
  #pragma unroll
  for (int off = 1; off < 1024; off <<= 1) {
    int t = (tid >= off) ? buf[tid - off] : 0;
    __syncthreads();
    buf[tid] += t;
    __syncthreads();
  }
  if (i < n) base[i] = buf[tid] - v;
  if (tid == 1023) partials[blockIdx.x] = buf[tid];
}

__global__ void k_scan_partials(int* __restrict__ partials, int nb) {
  __shared__ int buf[128];
  int tid = threadIdx.x;
  int v = (tid < nb) ? partials[tid] : 0;
  buf[tid] = v;
  __syncthreads();
  #pragma unroll
  for (int off = 1; off < 128; off <<= 1) {
    int t = (tid >= off) ? buf[tid - off] : 0;
    __syncthreads();
    buf[tid] += t;
    __syncthreads();
  }
  if (tid < nb) partials[tid] = buf[tid] - v;
}

__global__ void k_finalize_base(int* __restrict__ base, const int* __restrict__ partials,
    const int* __restrict__ deg, float* __restrict__ dinv, int n, int E) {
  int i = blockIdx.x * blockDim.x + threadIdx.x;
  if (i < n) {
    base[i] += partials[i >> 10];
    dinv[i] = rsqrtf((float)(deg[i] + 1));
  } else if (i == n) {
    base[n] = E;
  }
}

__global__ void k_scatter(const int* __restrict__ src, const int* __restrict__ dst,
    const int* __restrict__ rank, const int* __restrict__ base,
    int* __restrict__ ssrc, int E) {
  int e = blockIdx.x * blockDim.x + threadIdx.x;
  if (e < E) ssrc[base[dst[e]] + rank[e]] = src[e];
}

// ---------------- MFMA fp16 GEMM: g16 = sliced( (A @ W) * dinv[row] ) ---------
template <typename AT>
__global__ __launch_bounds__(256) void k_gemm_mfma(
    const AT* __restrict__ A, const _Float16* __restrict__ Wt,
    const float* __restrict__ dinv, _Float16* __restrict__ g16, int N) {
  __shared__ _Float16 As[64][136];
  __shared__ _Float16 Ws[128][136];
  const int tid = threadIdx.x;
  const int row0 = blockIdx.x * 64;

  if constexpr (sizeof(AT) == 4) {   // fp32 input: load + cast
    #pragma unroll
    for (int i = 0; i < 8; i++) {
      int idx = tid + i * 256;       // 0..2047
      int row = idx >> 5;
      int c4 = idx & 31;
      int gr = row0 + row; gr = (gr < N) ? gr : (N - 1);
      float4 v = *(const float4*)((const float*)A + (size_t)gr * NFEAT + c4 * 4);
      _Float16* p = &As[row][c4 * 4];
      p[0] = (_Float16)v.x; p[1] = (_Float16)v.y;
      p[2] = (_Float16)v.z; p[3] = (_Float16)v.w;
    }
  } else {                           // fp16 input: straight copy
    #pragma unroll
    for (int i = 0; i < 4; i++) {
      int idx = tid + i * 256;
      int row = idx >> 4;
      int c8 = idx & 15;
      int gr = row0 + row; gr = (gr < N) ? gr : (N - 1);
      *(uint4*)&As[row][c8 * 8] =
          *(const uint4*)((const _Float16*)A + (size_t)gr * NFEAT + c8 * 8);
    }
  }
  #pragma unroll
  for (int i = 0; i < 8; i++) {
    int idx = tid + i * 256;
    int row = idx >> 4;
    int c8 = idx & 15;
    *(uint4*)&Ws[row][c8 * 8] = *(const uint4*)(Wt + (size_t)row * 128 + c8 * 8);
  }
  __syncthreads();

  const int wv = tid >> 6;
  const int lane = tid & 63;
  const int m = lane & 15;
  const int q = lane >> 4;

  v4f acc[8] = {};
  const _Float16* arow = &As[wv * 16 + m][0];
  #pragma unroll
  for (int kt = 0; kt < 4; kt++) {
    v8hf af = *(const v8hf*)(arow + kt * 32 + q * 8);
    #pragma unroll
    for (int ct = 0; ct < 8; ct++) {
      v8hf bf = *(const v8hf*)(&Ws[ct * 16 + m][kt * 32 + q * 8]);
      acc[ct] = __builtin_amdgcn_mfma_f32_16x16x32_f16(af, bf, acc[ct], 0, 0, 0);
    }
  }

  int nd[4]; float dv[4];
  #pragma unroll
  for (int r = 0; r < 4; r++) {
    nd[r] = row0 + wv * 16 + q * 4 + r;
    int c = (nd[r] < N) ? nd[r] : (N - 1);
    dv[r] = dinv[c];
  }
  #pragma unroll
  for (int ct = 0; ct < 8; ct++)
    #pragma unroll
    for (int r = 0; r < 4; r++)
      if (nd[r] < N)
        g16[((size_t)ct * N + nd[r]) * 16 + m] = (_Float16)(acc[ct][r] * dv[r]);
}

// ---------------- XCD-sliced agg, lane-private accumulation ------------------
// Wave = 8 nodes x 8 half2-features of slice s (= blockIdx%8, XCD-pinned).
// Lane group p = lane>>3 owns node n0+p; lane d = lane&7 owns feature pair d.
// Each lane privately accumulates -> NO cross-lane reduction, no shuffles.
__global__ __launch_bounds__(256) void k_agg_slice(
    const __half2* __restrict__ g16, const float* __restrict__ dinv,
    const int* __restrict__ base, const int* __restrict__ ssrc,
    const float* __restrict__ bias, __half2* __restrict__ hB, int N) {
  const int lane = threadIdx.x & 63;
  const int wv = threadIdx.x >> 6;
  const int s = blockIdx.x & 7;
  const int p = lane >> 3, d = lane & 7;
  const int n = (blockIdx.x >> 3) * 32 + wv * 8 + p;
  const bool act = (n < N);
  const int nc = act ? n : (N - 1);
  const __half2* table = g16 + (size_t)s * N * 8;

  float2 acc = __half22float2(table[(size_t)nc * 8 + d]);   // self term
  int e = base[nc], b1 = base[nc + 1];
  if (!act) { e = 0; b1 = 0; }
  for (; e + 4 <= b1; e += 4) {
    int s0 = ssrc[e], s1 = ssrc[e + 1], s2 = ssrc[e + 2], s3 = ssrc[e + 3];
    float2 f0 = __half22float2(table[(size_t)s0 * 8 + d]);
    float2 f1 = __half22float2(table[(size_t)s1 * 8 + d]);
    float2 f2 = __half22float2(table[(size_t)s2 * 8 + d]);
    float2 f3 = __half22float2(table[(size_t)s3 * 8 + d]);
    acc.x += (f0.x + f1.x) + (f2.x + f3.x);
    acc.y += (f0.y + f1.y) + (f2.y + f3.y);
  }
  for (; e < b1; ++e) {
    float2 f = __half22float2(table[(size_t)ssrc[e] * 8 + d]);
    acc.x += f.x; acc.y += f.y;
  }
  if (act) {
    float dvn = dinv[n];
    float2 bb = *(const float2*)(bias + s * 16 + d * 2);
    hB[(size_t)n * 64 + s * 8 + d] =
        __floats2half2_rn(fmaxf(acc.x * dvn + bb.x, 0.f),
                          fmaxf(acc.y * dvn + bb.y, 0.f));
  }
}

// ---------------- layer-2 sliced agg fused with final linear -----------------
__global__ __launch_bounds__(256) void k_agg_final_slice(
    const __half2* __restrict__ g16, const float* __restrict__ dinv,
    const int* __restrict__ base, const int* __restrict__ ssrc,
    const float* __restrict__ bias, const float* __restrict__ wlin,
    const float* __restrict__ blin, float* __restrict__ out, int N) {
  const int lane = threadIdx.x & 63;
  const int wv = threadIdx.x >> 6;
  const int s = blockIdx.x & 7;
  const int p = lane >> 3, d = lane & 7;
  const int n = (blockIdx.x >> 3) * 32 + wv * 8 + p;
  const bool act = (n < N);
  const int nc = act ? n : (N - 1);
  const __half2* table = g16 + (size_t)s * N * 8;

  float2 acc = __half22float2(table[(size_t)nc * 8 + d]);
  int e = base[nc], b1 = base[nc + 1];
  if (!act) { e = 0; b1 = 0; }
  for (; e + 4 <= b1; e += 4) {
    int s0 = ssrc[e], s1 = ssrc[e + 1], s2 = ssrc[e + 2], s3 = ssrc[e + 3];
    float2 f0 = __half22float2(table[(size_t)s0 * 8 + d]);
    float2 f1 = __half22float2(table[(size_t)s1 * 8 + d]);
    float2 f2 = __half22float2(table[(size_t)s2 * 8 + d]);
    float2 f3 = __half22float2(table[(size_t)s3 * 8 + d]);
    acc.x += (f0.x + f1.x) + (f2.x + f3.x);
    acc.y += (f0.y + f1.y) + (f2.y + f3.y);
  }
  for (; e < b1; ++e) {
    float2 f = __half22float2(table[(size_t)ssrc[e] * 8 + d]);
    acc.x += f.x; acc.y += f.y;
  }
  if (act) {
    float dvn = dinv[n];
    float2 bb = *(const float2*)(bias + s * 16 + d * 2);
    float2 wl = *(const float2*)(wlin + s * 16 + d * 2);
    float pv = fmaxf(acc.x * dvn + bb.x, 0.f) * wl.x +
               fmaxf(acc.y * dvn + bb.y, 0.f) * wl.y;
    #pragma unroll
    for (int m = 1; m <= 4; m <<= 1) pv += __shfl_xor(pv, m, 64);
    if (d == 0) atomicAdd(out + n, pv + (s == 0 ? blin[0] : 0.f));
  }
}

extern "C" void kernel_launch(void* const* d_in, const int* in_sizes, int n_in,
                              void* d_out, int out_size, void* d_ws, size_t ws_size,
                              hipStream_t stream) {
  const float* x    = (const float*)d_in[0];
  const int*   ei   = (const int*)d_in[1];
  const float* W1   = (const float*)d_in[2];
  const float* b1   = (const float*)d_in[3];
  const float* W2   = (const float*)d_in[4];
  const float* b2   = (const float*)d_in[5];
  const float* Wlin = (const float*)d_in[6];
  const float* blin = (const float*)d_in[7];
  const int N = in_sizes[0] / NFEAT;
  const int E = in_sizes[1] / 2;
  const int* src = ei;
  const int* dst = ei + E;

  // workspace layout (4B units)
  int* ws_i = (int*)d_ws;
  size_t off = 0;
  int* deg      = ws_i + off; off += N;
  int* base     = ws_i + off; off += (size_t)N + 1;
  off = (off + 3) & ~(size_t)3;
  int* partials = ws_i + off; off += 128;
  int* ssrc     = ws_i + off; off += E;
  float* dinv   = (float*)(ws_i + off); off += N;
  off = (off + 3) & ~(size_t)3;
  _Float16* Wt1 = (_Float16*)(ws_i + off); off += 8192;
  _Float16* Wt2 = (_Float16*)(ws_i + off); off += 8192;
  _Float16* g16 = (_Float16*)(ws_i + off); off += (size_t)N * 64;
  _Float16* hB  = (_Float16*)(ws_i + off); off += (size_t)N * 64;
  int* rank     = (int*)g16;   // E ints, consumed before GEMM1 writes g16

  hipMemsetAsync(deg, 0, (size_t)N * sizeof(int), stream);
  hipMemsetAsync(d_out, 0, (size_t)N * sizeof(float), stream);

  const int tpbE = 256;
  const int gE = (E + tpbE - 1) / tpbE;
  k_deg_rank<<<gE, tpbE, 0, stream>>>(dst, deg, rank, E);
  k_prep_w<<<128, 256, 0, stream>>>(W1, W2, Wt1, Wt2);

  const int nb = (N + 1023) / 1024;
  k_scan_blocks<<<nb, 1024, 0, stream>>>(deg, base, partials, N);
  k_scan_partials<<<1, 128, 0, stream>>>(partials, nb);
  k_finalize_base<<<((N + 1) + 255) / 256, 256, 0, stream>>>(base, partials, deg, dinv, N, E);
  k_scatter<<<gE, tpbE, 0, stream>>>(src, dst, rank, base, ssrc, E);

  const int gg = (N + 63) / 64;
  const int ga = 8 * ((N + 31) / 32);
  // layer 1
  k_gemm_mfma<float><<<gg, 256, 0, stream>>>(x, Wt1, dinv, g16, N);
  k_agg_slice<<<ga, 256, 0, stream>>>((const __half2*)g16, dinv, base, ssrc, b1,
                                      (__half2*)hB, N);
  // layer 2 + fused final linear
  k_gemm_mfma<_Float16><<<gg, 256, 0, stream>>>(hB, Wt2, dinv, g16, N);
  k_agg_final_slice<<<ga, 256, 0, stream>>>((const __half2*)g16, dinv, base, ssrc, b2,
                                            Wlin, blin, (float*)d_out, N);
}

// Round 7
// 426.172 us; speedup vs baseline: 1.8118x; 1.0128x over previous
//
#include <hip/hip_runtime.h>
#include <hip/hip_fp16.h>

#define NFEAT 128

typedef _Float16 v8hf __attribute__((ext_vector_type(8)));
typedef float v4f __attribute__((ext_vector_type(4)));

// ---------------- degree histogram + per-edge rank ----------------
__global__ void k_deg_rank(const int* __restrict__ dst, int* __restrict__ deg,
                           int* __restrict__ rank, int E) {
  int e = blockIdx.x * blockDim.x + threadIdx.x;
  if (e < E) rank[e] = atomicAdd(&deg[dst[e]], 1);
}

// ---------------- fill ssrc with sentinel N (pad slots gather zero row) ------
__global__ void k_fill(int* __restrict__ p, int v, int n) {
  int i = blockIdx.x * 256 + threadIdx.x;
  if (i < n) p[i] = v;
}

// ---------------- W transpose + fp16 cast: Wt[n][k] = half(W[k][n]) ----------
__global__ void k_prep_w(const float* __restrict__ W1, const float* __restrict__ W2,
                         _Float16* __restrict__ Wt1, _Float16* __restrict__ Wt2) {
  int idx = blockIdx.x * 256 + threadIdx.x;     // 0..32767
  const float* W = (idx < 16384) ? W1 : W2;
  _Float16* Wt = (idx < 16384) ? Wt1 : Wt2;
  int i = idx & 16383;
  int k = i >> 7, n = i & 127;
  Wt[n * 128 + k] = (_Float16)W[k * 128 + n];
}

// ---------------- 2-level exclusive scan over PADDED degrees -----------------
// Scans M = N+1 values: val(i) = i<N ? (deg[i]+7)&~7 : 0  -> base[0..N].
__global__ __launch_bounds__(1024) void k_scan_blocks(const int* __restrict__ deg,
    int* __restrict__ base, int* __restrict__ partials, int n) {
  __shared__ int buf[1024];
  int tid = threadIdx.x;
  int i = blockIdx.x * 1024 + tid;
  int v = (i < n) ? ((deg[i] + 7) & ~7) : 0;
  buf[tid] = v;
  __syncthreads();
  #pragma unroll
  for (int off = 1; off < 1024; off <<= 1) {
    int t = (tid >= off) ? buf[tid - off] : 0;
    __syncthreads();
    buf[tid] += t;
    __syncthreads();
  }
  if (i <= n) base[i] = buf[tid] - v;
  if (tid == 1023) partials[blockIdx.x] = buf[tid];
}

__global__ void k_scan_partials(int* __restrict__ partials, int nb) {
  __shared__ int buf[128];
  int tid = threadIdx.x;
  int v = (tid < nb) ? partials[tid] : 0;
  buf[tid] = v;
  __syncthreads();
  #pragma unroll
  for (int off = 1; off < 128; off <<= 1) {
    int t = (tid >= off) ? buf[tid - off] : 0;
    __syncthreads();
    buf[tid] += t;
    __syncthreads();
  }
  if (tid < nb) partials[tid] = buf[tid] - v;
}

__global__ void k_finalize_base(int* __restrict__ base, const int* __restrict__ partials,
    const int* __restrict__ deg, float* __restrict__ dinv, int n) {
  int i = blockIdx.x * blockDim.x + threadIdx.x;
  if (i <= n) {
    base[i] += partials[i >> 10];
    if (i < n) dinv[i] = rsqrtf((float)(deg[i] + 1));
  }
}

__global__ void k_scatter(const int* __restrict__ src, const int* __restrict__ dst,
    const int* __restrict__ rank, const int* __restrict__ base,
    int* __restrict__ ssrc, int E) {
  int e = blockIdx.x * blockDim.x + threadIdx.x;
  if (e < E) ssrc[base[dst[e]] + rank[e]] = src[e];
}

// ---------------- zero sentinel row N of the sliced table --------------------
__global__ void k_zero_row(_Float16* __restrict__ g16, int N) {
  int i = threadIdx.x;           // 0..127
  int s = i >> 4, m = i & 15;
  g16[((size_t)s * (N + 1) + N) * 16 + m] = (_Float16)0.f;
}

// ---------------- MFMA fp16 GEMM: g16 = sliced( (A @ W) * dinv[row] ) ---------
// Slice stride is (N+1) rows (row N = zero sentinel).
template <typename AT>
__global__ __launch_bounds__(256) void k_gemm_mfma(
    const AT* __restrict__ A, const _Float16* __restrict__ Wt,
    const float* __restrict__ dinv, _Float16* __restrict__ g16, int N) {
  __shared__ _Float16 As[64][136];
  __shared__ _Float16 Ws[128][136];
  const int tid = threadIdx.x;
  const int row0 = blockIdx.x * 64;

  if constexpr (sizeof(AT) == 4) {   // fp32 input: load + cast
    #pragma unroll
    for (int i = 0; i < 8; i++) {
      int idx = tid + i * 256;       // 0..2047
      int row = idx >> 5;
      int c4 = idx & 31;
      int gr = row0 + row; gr = (gr < N) ? gr : (N - 1);
      float4 v = *(const float4*)((const float*)A + (size_t)gr * NFEAT + c4 * 4);
      _Float16* p = &As[row][c4 * 4];
      p[0] = (_Float16)v.x; p[1] = (_Float16)v.y;
      p[2] = (_Float16)v.z; p[3] = (_Float16)v.w;
    }
  } else {                           // fp16 input: straight copy
    #pragma unroll
    for (int i = 0; i < 4; i++) {
      int idx = tid + i * 256;
      int row = idx >> 4;
      int c8 = idx & 15;
      int gr = row0 + row; gr = (gr < N) ? gr : (N - 1);
      *(uint4*)&As[row][c8 * 8] =
          *(const uint4*)((const _Float16*)A + (size_t)gr * NFEAT + c8 * 8);
    }
  }
  #pragma unroll
  for (int i = 0; i < 8; i++) {
    int idx = tid + i * 256;
    int row = idx >> 4;
    int c8 = idx & 15;
    *(uint4*)&Ws[row][c8 * 8] = *(const uint4*)(Wt + (size_t)row * 128 + c8 * 8);
  }
  __syncthreads();

  const int wv = tid >> 6;
  const int lane = tid & 63;
  const int m = lane & 15;
  const int q = lane >> 4;

  v4f acc[8] = {};
  const _Float16* arow = &As[wv * 16 + m][0];
  #pragma unroll
  for (int kt = 0; kt < 4; kt++) {
    v8hf af = *(const v8hf*)(arow + kt * 32 + q * 8);
    #pragma unroll
    for (int ct = 0; ct < 8; ct++) {
      v8hf bf = *(const v8hf*)(&Ws[ct * 16 + m][kt * 32 + q * 8]);
      acc[ct] = __builtin_amdgcn_mfma_f32_16x16x32_f16(af, bf, acc[ct], 0, 0, 0);
    }
  }

  int nd[4]; float dv[4];
  #pragma unroll
  for (int r = 0; r < 4; r++) {
    nd[r] = row0 + wv * 16 + q * 4 + r;
    int c = (nd[r] < N) ? nd[r] : (N - 1);
    dv[r] = dinv[c];
  }
  #pragma unroll
  for (int ct = 0; ct < 8; ct++)
    #pragma unroll
    for (int r = 0; r < 4; r++)
      if (nd[r] < N)
        g16[((size_t)ct * (N + 1) + nd[r]) * 16 + m] = (_Float16)(acc[ct][r] * dv[r]);
}

// ---------------- XCD-sliced agg, padded CSR, 8-wide gather batches ----------
// Wave = 8 nodes x 8 half2-features of slice s (= blockIdx%8, XCD-pinned).
// Padded degrees (x8) -> aligned int4 index loads, 8 independent gathers/iter,
// no tail, lane-private fp32 accumulation, zero shuffles.
__global__ __launch_bounds__(256) void k_agg_slice(
    const __half2* __restrict__ g16, const float* __restrict__ dinv,
    const int* __restrict__ base, const int* __restrict__ ssrc,
    const float* __restrict__ bias, __half2* __restrict__ hB, int N) {
  const int lane = threadIdx.x & 63;
  const int wv = threadIdx.x >> 6;
  const int s = blockIdx.x & 7;
  const int p = lane >> 3, d = lane & 7;
  const int n = (blockIdx.x >> 3) * 32 + wv * 8 + p;
  const bool act = (n < N);
  const int nc = act ? n : (N - 1);
  const __half2* table = g16 + (size_t)s * (N + 1) * 8;

  float2 a0 = __half22float2(table[(size_t)nc * 8 + d]);   // self term
  float2 a1 = make_float2(0.f, 0.f);
  int e = base[nc], b1e = base[nc + 1];
  if (!act) b1e = e;
  for (; e < b1e; e += 8) {
    int4 ia = *(const int4*)(ssrc + e);
    int4 ib = *(const int4*)(ssrc + e + 4);
    float2 f0 = __half22float2(table[(size_t)ia.x * 8 + d]);
    float2 f1 = __half22float2(table[(size_t)ia.y * 8 + d]);
    float2 f2 = __half22float2(table[(size_t)ia.z * 8 + d]);
    float2 f3 = __half22float2(table[(size_t)ia.w * 8 + d]);
    float2 f4 = __half22float2(table[(size_t)ib.x * 8 + d]);
    float2 f5 = __half22float2(table[(size_t)ib.y * 8 + d]);
    float2 f6 = __half22float2(table[(size_t)ib.z * 8 + d]);
    float2 f7 = __half22float2(table[(size_t)ib.w * 8 + d]);
    a0.x += (f0.x + f1.x) + (f2.x + f3.x);
    a0.y += (f0.y + f1.y) + (f2.y + f3.y);
    a1.x += (f4.x + f5.x) + (f6.x + f7.x);
    a1.y += (f4.y + f5.y) + (f6.y + f7.y);
  }
  if (act) {
    float dvn = dinv[n];
    float2 bb = *(const float2*)(bias + s * 16 + d * 2);
    hB[(size_t)n * 64 + s * 8 + d] =
        __floats2half2_rn(fmaxf((a0.x + a1.x) * dvn + bb.x, 0.f),
                          fmaxf((a0.y + a1.y) * dvn + bb.y, 0.f));
  }
}

// ---------------- layer-2 sliced agg fused with final linear -----------------
__global__ __launch_bounds__(256) void k_agg_final_slice(
    const __half2* __restrict__ g16, const float* __restrict__ dinv,
    const int* __restrict__ base, const int* __restrict__ ssrc,
    const float* __restrict__ bias, const float* __restrict__ wlin,
    const float* __restrict__ blin, float* __restrict__ out, int N) {
  const int lane = threadIdx.x & 63;
  const int wv = threadIdx.x >> 6;
  const int s = blockIdx.x & 7;
  const int p = lane >> 3, d = lane & 7;
  const int n = (blockIdx.x >> 3) * 32 + wv * 8 + p;
  const bool act = (n < N);
  const int nc = act ? n : (N - 1);
  const __half2* table = g16 + (size_t)s * (N + 1) * 8;

  float2 a0 = __half22float2(table[(size_t)nc * 8 + d]);
  float2 a1 = make_float2(0.f, 0.f);
  int e = base[nc], b1e = base[nc + 1];
  if (!act) b1e = e;
  for (; e < b1e; e += 8) {
    int4 ia = *(const int4*)(ssrc + e);
    int4 ib = *(const int4*)(ssrc + e + 4);
    float2 f0 = __half22float2(table[(size_t)ia.x * 8 + d]);
    float2 f1 = __half22float2(table[(size_t)ia.y * 8 + d]);
    float2 f2 = __half22float2(table[(size_t)ia.z * 8 + d]);
    float2 f3 = __half22float2(table[(size_t)ia.w * 8 + d]);
    float2 f4 = __half22float2(table[(size_t)ib.x * 8 + d]);
    float2 f5 = __half22float2(table[(size_t)ib.y * 8 + d]);
    float2 f6 = __half22float2(table[(size_t)ib.z * 8 + d]);
    float2 f7 = __half22float2(table[(size_t)ib.w * 8 + d]);
    a0.x += (f0.x + f1.x) + (f2.x + f3.x);
    a0.y += (f0.y + f1.y) + (f2.y + f3.y);
    a1.x += (f4.x + f5.x) + (f6.x + f7.x);
    a1.y += (f4.y + f5.y) + (f6.y + f7.y);
  }
  if (act) {
    float dvn = dinv[n];
    float2 bb = *(const float2*)(bias + s * 16 + d * 2);
    float2 wl = *(const float2*)(wlin + s * 16 + d * 2);
    float pv = fmaxf((a0.x + a1.x) * dvn + bb.x, 0.f) * wl.x +
               fmaxf((a0.y + a1.y) * dvn + bb.y, 0.f) * wl.y;
    #pragma unroll
    for (int m = 1; m <= 4; m <<= 1) pv += __shfl_xor(pv, m, 64);
    if (d == 0) atomicAdd(out + n, pv + (s == 0 ? blin[0] : 0.f));
  }
}

extern "C" void kernel_launch(void* const* d_in, const int* in_sizes, int n_in,
                              void* d_out, int out_size, void* d_ws, size_t ws_size,
                              hipStream_t stream) {
  const float* x    = (const float*)d_in[0];
  const int*   ei   = (const int*)d_in[1];
  const float* W1   = (const float*)d_in[2];
  const float* b1   = (const float*)d_in[3];
  const float* W2   = (const float*)d_in[4];
  const float* b2   = (const float*)d_in[5];
  const float* Wlin = (const float*)d_in[6];
  const float* blin = (const float*)d_in[7];
  const int N = in_sizes[0] / NFEAT;
  const int E = in_sizes[1] / 2;
  const int* src = ei;
  const int* dst = ei + E;
  const int Epad = E + 8 * N + 8;   // padded CSR capacity

  // workspace layout (4B units)
  int* ws_i = (int*)d_ws;
  size_t off = 0;
  int* deg      = ws_i + off; off += N;
  int* base     = ws_i + off; off += (size_t)N + 1;
  off = (off + 3) & ~(size_t)3;
  int* partials = ws_i + off; off += 128;
  int* ssrc     = ws_i + off; off += Epad;
  float* dinv   = (float*)(ws_i + off); off += N;
  off = (off + 3) & ~(size_t)3;
  _Float16* Wt1 = (_Float16*)(ws_i + off); off += 8192;
  _Float16* Wt2 = (_Float16*)(ws_i + off); off += 8192;
  _Float16* g16 = (_Float16*)(ws_i + off); off += (size_t)(N + 1) * 64 + 32;
  _Float16* hB  = (_Float16*)(ws_i + off); off += (size_t)N * 64;
  int* rank     = (int*)g16;   // E ints, consumed by k_scatter before g16 written

  hipMemsetAsync(deg, 0, (size_t)N * sizeof(int), stream);
  hipMemsetAsync(d_out, 0, (size_t)N * sizeof(float), stream);

  const int tpbE = 256;
  const int gE = (E + tpbE - 1) / tpbE;
  k_deg_rank<<<gE, tpbE, 0, stream>>>(dst, deg, rank, E);
  k_fill<<<(Epad + 255) / 256, 256, 0, stream>>>(ssrc, N, Epad);  // sentinel fill
  k_prep_w<<<128, 256, 0, stream>>>(W1, W2, Wt1, Wt2);

  const int nb = (N + 1 + 1023) / 1024;
  k_scan_blocks<<<nb, 1024, 0, stream>>>(deg, base, partials, N);
  k_scan_partials<<<1, 128, 0, stream>>>(partials, nb);
  k_finalize_base<<<((N + 1) + 255) / 256, 256, 0, stream>>>(base, partials, deg, dinv, N);
  k_scatter<<<gE, tpbE, 0, stream>>>(src, dst, rank, base, ssrc, E);
  k_zero_row<<<1, 128, 0, stream>>>(g16, N);   // after scatter (rank aliased g16)

  const int gg = (N + 63) / 64;
  const int ga = 8 * ((N + 31) / 32);
  // layer 1
  k_gemm_mfma<float><<<gg, 256, 0, stream>>>(x, Wt1, dinv, g16, N);
  k_agg_slice<<<ga, 256, 0, stream>>>((const __half2*)g16, dinv, base, ssrc, b1,
                                      (__half2*)hB, N);
  // layer 2 + fused final linear
  k_gemm_mfma<_Float16><<<gg, 256, 0, stream>>>(hB, Wt2, dinv, g16, N);
  k_agg_final_slice<<<ga, 256, 0, stream>>>((const __half2*)g16, dinv, base, ssrc, b2,
                                            Wlin, blin, (float*)d_out, N);
}